// Round 1
// baseline (745.884 us; speedup 1.0000x reference)
//
#include <hip/hip_runtime.h>
#include <hip/hip_bf16.h>

// Problem: B=16384, A=4096, D=512, H=512
//   q = l2norm(x @ Wq^T); k = l2norm(anchors @ Wk^T)
//   sims = q @ k^T  (output #2, [B,A] f32)
//   w = softmax(round(sims/0.05)*0.05); out = w @ values (output #1, [B,H] f32)
// Strategy: bf16 MFMA everywhere (fp32 accum). round() bounds logits to [-1,1]
// so no online max is needed: accumulate sum(exp) and exp@values directly.

#define B_N 16384
#define A_N 4096
#define D_N 512
#define H_N 512

typedef __attribute__((ext_vector_type(8))) short bf16x8;
typedef __attribute__((ext_vector_type(4))) float f32x4;

__device__ __forceinline__ short f2bf(float f) {
  union { float f; unsigned int u; } v;
  v.f = f;
  unsigned int r = v.u + 0x7FFFu + ((v.u >> 16) & 1u);   // RNE
  return (short)(r >> 16);
}
__device__ __forceinline__ float bf2f(short s) {
  union { float f; unsigned int u; } v;
  v.u = ((unsigned int)(unsigned short)s) << 16;
  return v.f;
}

// async global->LDS, 16B per lane (wave writes base + lane*16 contiguously)
__device__ __forceinline__ void async_copy16(const void* g, void* l) {
  __builtin_amdgcn_global_load_lds(
      (const __attribute__((address_space(1))) unsigned int*)g,
      (__attribute__((address_space(3))) unsigned int*)l, 16, 0, 0);
}

// ---------------------------------------------------------------------------
// W [512][512] f32 -> bf16, cols pre-swizzled (col ^= (row&7)<<3 within 64-col
// groups) so proj_norm can global_load_lds linearly and ds_read swizzled.
__global__ void convert_w_kernel(const float* __restrict__ W, short* __restrict__ out) {
  int u = blockIdx.x * 256 + threadIdx.x;   // 32768 units of 8 elems
  int row = u >> 6;
  int cu = u & 63;
  const float4* src = (const float4*)(W + (size_t)row * 512 + cu * 8);
  float4 a = src[0], b = src[1];
  bf16x8 o;
  o[0]=f2bf(a.x); o[1]=f2bf(a.y); o[2]=f2bf(a.z); o[3]=f2bf(a.w);
  o[4]=f2bf(b.x); o[5]=f2bf(b.y); o[6]=f2bf(b.z); o[7]=f2bf(b.w);
  int cu2 = cu ^ (row & 7);
  *(bf16x8*)(out + (size_t)row * 512 + cu2 * 8) = o;
}

// ---------------------------------------------------------------------------
// values [4096][512] f32 -> vt [512][4096] bf16, pre-swizzled within 64-anchor
// groups (col ^= (h&7)<<3).
__global__ void transpose_values_kernel(const float* __restrict__ vals, short* __restrict__ vt) {
  __shared__ float tile[64][65];
  int t = threadIdx.x;
  int a0 = (blockIdx.x & 63) * 64;
  int h0 = (blockIdx.x >> 6) * 64;
#pragma unroll
  for (int r = 0; r < 4; ++r) {
    int ar = r * 16 + (t >> 4);
    int hc = (t & 15) * 4;
    float4 v = *(const float4*)(vals + (size_t)(a0 + ar) * 512 + h0 + hc);
    tile[ar][hc + 0] = v.x; tile[ar][hc + 1] = v.y;
    tile[ar][hc + 2] = v.z; tile[ar][hc + 3] = v.w;
  }
  __syncthreads();
#pragma unroll
  for (int r = 0; r < 2; ++r) {
    int u = r * 256 + t;
    int hr = u >> 3;       // 0..63
    int cu = u & 7;
    int h = h0 + hr;
    bf16x8 o;
#pragma unroll
    for (int j = 0; j < 8; ++j) o[j] = f2bf(tile[cu * 8 + j][hr]);
    int cu2 = cu ^ (h & 7);
    *(bf16x8*)(vt + (size_t)h * 4096 + a0 + cu2 * 8) = o;
  }
}

// ---------------------------------------------------------------------------
// P = l2norm_rows(X @ W^T) in bf16. Block = 256thr (4 waves), 64 rows, all 512
// cols resident in acc regs so the row norm is computed without a 2nd pass.
// SWZ=1: output cols swizzled (K for the attention kernel's LDS staging).
template <int SWZ>
__global__ __launch_bounds__(256, 2) void proj_norm_kernel(
    const float* __restrict__ X, const short* __restrict__ Wcv, short* __restrict__ out) {
  __shared__ __align__(16) short xs[64 * 64];     // x chunk [64 rows][64 k] bf16
  __shared__ __align__(16) short wsb[512 * 64];   // W chunk [512 h][64 k] bf16
  const int t = threadIdx.x;
  const int lane = t & 63;
  const int wv = t >> 6;
  const int l15 = lane & 15;
  const int lhi = lane >> 4;
  const int row0 = blockIdx.x * 64;

  const f32x4 ZZ = {0.f, 0.f, 0.f, 0.f};
  f32x4 acc[32];
#pragma unroll
  for (int i = 0; i < 32; ++i) acc[i] = ZZ;

  for (int kc = 0; kc < 8; ++kc) {
    const int k0 = kc * 64;
    // stage x chunk: convert f32->bf16, swizzled ds_write_b128
#pragma unroll
    for (int i = 0; i < 2; ++i) {
      int u = i * 256 + t;
      int row = u >> 3, cu = u & 7;
      const float4* src = (const float4*)(X + (size_t)(row0 + row) * 512 + k0 + cu * 8);
      float4 a = src[0], b = src[1];
      bf16x8 o;
      o[0]=f2bf(a.x); o[1]=f2bf(a.y); o[2]=f2bf(a.z); o[3]=f2bf(a.w);
      o[4]=f2bf(b.x); o[5]=f2bf(b.y); o[6]=f2bf(b.z); o[7]=f2bf(b.w);
      *(bf16x8*)(&xs[row * 64 + ((cu ^ (row & 7)) * 8)]) = o;
    }
    // stage W chunk: linear async copy from pre-swizzled bf16 image
#pragma unroll
    for (int i = 0; i < 16; ++i) {
      int u = i * 256 + t;
      async_copy16((const char*)Wcv + (size_t)(u >> 3) * 1024 + k0 * 2 + (u & 7) * 16,
                   (char*)wsb + u * 16);
    }
    __syncthreads();

    bf16x8 af[2];
    const int arow = wv * 16 + l15;
#pragma unroll
    for (int kk = 0; kk < 2; ++kk)
      af[kk] = *(const bf16x8*)(&xs[arow * 64 + (((kk * 4 + lhi) ^ (arow & 7)) * 8)]);
#pragma unroll
    for (int nt = 0; nt < 32; ++nt) {
      const int brow = nt * 16 + l15;
      const int bs = brow & 7;
#pragma unroll
      for (int kk = 0; kk < 2; ++kk) {
        bf16x8 bf = *(const bf16x8*)(&wsb[brow * 64 + (((kk * 4 + lhi) ^ bs) * 8)]);
        acc[nt] = __builtin_amdgcn_mfma_f32_16x16x32_bf16(af[kk], bf, acc[nt], 0, 0, 0);
      }
    }
    __syncthreads();
  }

  // row sum-of-squares: lane holds rows (lhi*4+r), cols (nt*16+l15)
  float ssq[4] = {0.f, 0.f, 0.f, 0.f};
#pragma unroll
  for (int nt = 0; nt < 32; ++nt)
#pragma unroll
    for (int r = 0; r < 4; ++r) ssq[r] += acc[nt][r] * acc[nt][r];
#pragma unroll
  for (int r = 0; r < 4; ++r) {
    ssq[r] += __shfl_xor(ssq[r], 1);
    ssq[r] += __shfl_xor(ssq[r], 2);
    ssq[r] += __shfl_xor(ssq[r], 4);
    ssq[r] += __shfl_xor(ssq[r], 8);
  }
  float scale[4];
#pragma unroll
  for (int r = 0; r < 4; ++r) scale[r] = 1.0f / fmaxf(sqrtf(ssq[r]), 1e-12f);

#pragma unroll
  for (int nt = 0; nt < 32; ++nt) {
#pragma unroll
    for (int r = 0; r < 4; ++r) {
      int grow = row0 + wv * 16 + lhi * 4 + r;
      int col = nt * 16 + l15;
      int ocol = SWZ ? (col ^ ((grow & 7) << 3)) : col;
      out[(size_t)grow * 512 + ocol] = f2bf(acc[nt][r] * scale[r]);
    }
  }
}

// ---------------------------------------------------------------------------
// Fused attention. 256 blocks x 512 thr (8 waves). BM=64 q-rows per block,
// 64-anchor chunks. Computes S^T = mfma(K,Q) so Q lives in regs (B-frags);
// PV computes out^T = mfma(V^T, w) so V is read once from LDS.
__global__ __launch_bounds__(512, 2) void attn_kernel(
    const short* __restrict__ qn,   // [B][512] bf16 plain
    const short* __restrict__ kn,   // [A][512] bf16 pre-swizzled
    const short* __restrict__ vt,   // [512][A] bf16 pre-swizzled
    float* __restrict__ outp,       // [B][512]
    float* __restrict__ sims) {     // [B][A]
  __shared__ __align__(16) short ks[64 * 512];   // K chunk  [64 a][512 d]
  __shared__ __align__(16) short vs[512 * 64];   // V^T chunk [512 h][64 a]
  __shared__ __align__(16) short wsm[64 * 64];   // w        [64 b][64 a]
  __shared__ __align__(16) float sbuf[64 * 68];  // sims bounce [64 b][64 a]
  __shared__ float sums[64];

  const int tid = threadIdx.x;
  const int lane = tid & 63;
  const int wid = tid >> 6;
  const int l15 = lane & 15;
  const int lhi = lane >> 4;
  const int b0 = blockIdx.x * 64;
  const int ag = wid >> 1;   // anchor-tile group (0..3)
  const int bg = wid & 1;    // 32-row group (0..1)

  if (tid < 64) sums[tid] = 0.0f;

  // Q fragments resident: rows bg*32 + tt*16 + l15, all 512 k
  bf16x8 qf[2][16];
#pragma unroll
  for (int tt = 0; tt < 2; ++tt) {
    const short* qp = qn + (size_t)(b0 + bg * 32 + tt * 16 + l15) * 512 + lhi * 8;
#pragma unroll
    for (int k = 0; k < 16; ++k) qf[tt][k] = *(const bf16x8*)(qp + k * 32);
  }

  const f32x4 ZZ = {0.f, 0.f, 0.f, 0.f};
  f32x4 accO[4][4];   // [h-tile][b-tile], out^T layout
#pragma unroll
  for (int i = 0; i < 4; ++i)
#pragma unroll
    for (int j = 0; j < 4; ++j) accO[i][j] = ZZ;
  float sum_p0 = 0.f, sum_p1 = 0.f;

  auto stage_k = [&](int cc) {
    const size_t kb = (size_t)cc * 64 * 1024;
#pragma unroll
    for (int i = 0; i < 8; ++i) {
      int u = i * 512 + tid;
      async_copy16((const char*)kn + kb + (size_t)(u >> 6) * 1024 + (u & 63) * 16,
                   (char*)ks + u * 16);
    }
  };
  auto stage_v = [&](int cc) {
    const size_t vb = (size_t)cc * 128;
#pragma unroll
    for (int i = 0; i < 8; ++i) {
      int u = i * 512 + tid;
      async_copy16((const char*)vt + (size_t)(u >> 3) * 8192 + vb + (u & 7) * 16,
                   (char*)vs + u * 16);
    }
  };

  stage_k(0);
  stage_v(0);

  for (int c = 0; c < 64; ++c) {
    const int c0 = c * 64;
    __syncthreads();   // staging landed (barrier drains vmcnt)

    // ---- QK^T (S^T): A = K rows from LDS, B = Q rows from regs ----
    f32x4 sAcc[2] = {ZZ, ZZ};
    const int arow = ag * 16 + l15;
    const int asw = arow & 7;
#pragma unroll
    for (int k = 0; k < 16; ++k) {
      bf16x8 kf = *(const bf16x8*)(&ks[arow * 512 + (((k * 4 + lhi) ^ asw) * 8)]);
#pragma unroll
      for (int tt = 0; tt < 2; ++tt)
        sAcc[tt] = __builtin_amdgcn_mfma_f32_16x16x32_bf16(kf, qf[tt][k], sAcc[tt], 0, 0, 0);
    }

    // ---- epilogue: sims to sbuf, w=exp(round) to wsm (bf16), partial sums ----
#pragma unroll
    for (int tt = 0; tt < 2; ++tt) {
      const int brow = bg * 32 + tt * 16 + l15;
      const int bsw = (brow & 7) << 3;
      float lsum = 0.f;
#pragma unroll
      for (int r = 0; r < 4; ++r) {
        const int aloc = ag * 16 + lhi * 4 + r;
        float s = sAcc[tt][r];
        sbuf[brow * 68 + aloc] = s;
        float rv = rintf(s * 20.0f) * 0.05f;   // bins of 0.05, RNE like jnp.round
        float wv = __expf(rv);                 // bounded: rv in [-1,1]
        short wb = f2bf(wv);
        wsm[brow * 64 + (aloc ^ bsw)] = wb;
        lsum += bf2f(wb);                      // sum consistent with bf16 PV operand
      }
      if (tt == 0) sum_p0 += lsum; else sum_p1 += lsum;
    }
    __syncthreads();

    // prefetch next K (ks no longer read this chunk) — hides under PV
    if (c + 1 < 64) stage_k(c + 1);

    // ---- coalesced sims write-out (64 rows x 256B) ----
    {
      const int row = tid >> 3;
      const int seg = tid & 7;
      const float* sp = &sbuf[row * 68 + seg * 8];
      float4 v0 = *(const float4*)sp;
      float4 v1 = *(const float4*)(sp + 4);
      float4* gp = (float4*)(sims + (size_t)(b0 + row) * 4096 + c0 + seg * 8);
      gp[0] = v0;
      gp[1] = v1;
    }

    // ---- PV: out^T += V^T(chunk) * w^T ----
#pragma unroll
    for (int kk = 0; kk < 2; ++kk) {
      bf16x8 wf[4];
#pragma unroll
      for (int bt = 0; bt < 4; ++bt) {
        const int br = bt * 16 + l15;
        wf[bt] = *(const bf16x8*)(&wsm[br * 64 + (((kk * 4 + lhi) ^ (br & 7)) * 8)]);
      }
#pragma unroll
      for (int ht = 0; ht < 4; ++ht) {
        const int hr = wid * 64 + ht * 16 + l15;
        bf16x8 vf = *(const bf16x8*)(&vs[hr * 64 + (((kk * 4 + lhi) ^ (hr & 7)) * 8)]);
#pragma unroll
        for (int bt = 0; bt < 4; ++bt)
          accO[ht][bt] = __builtin_amdgcn_mfma_f32_16x16x32_bf16(vf, wf[bt], accO[ht][bt], 0, 0, 0);
      }
    }
    __syncthreads();

    // prefetch next V (vs no longer read) — completes by next top barrier
    if (c + 1 < 64) stage_v(c + 1);
  }

  // ---- softmax denominators: reduce per-lane partials ----
  sum_p0 += __shfl_xor(sum_p0, 16);
  sum_p0 += __shfl_xor(sum_p0, 32);
  sum_p1 += __shfl_xor(sum_p1, 16);
  sum_p1 += __shfl_xor(sum_p1, 32);
  if (lane < 16) {
    atomicAdd(&sums[bg * 32 + lane], sum_p0);
    atomicAdd(&sums[bg * 32 + 16 + lane], sum_p1);
  }
  __syncthreads();

  // ---- write out: lane holds 4 consecutive h per (ht,bt) -> float4 ----
#pragma unroll
  for (int bt = 0; bt < 4; ++bt) {
    const int b = bt * 16 + l15;
    const float inv = 1.0f / sums[b];
#pragma unroll
    for (int ht = 0; ht < 4; ++ht) {
      f32x4 o = accO[ht][bt];
      float4 st;
      st.x = o[0] * inv; st.y = o[1] * inv; st.z = o[2] * inv; st.w = o[3] * inv;
      *(float4*)(outp + (size_t)(b0 + b) * 512 + wid * 64 + ht * 16 + lhi * 4) = st;
    }
  }
}

// ---------------------------------------------------------------------------
extern "C" void kernel_launch(void* const* d_in, const int* in_sizes, int n_in,
                              void* d_out, int out_size, void* d_ws, size_t ws_size,
                              hipStream_t stream) {
  const float* x       = (const float*)d_in[0];
  const float* anchors = (const float*)d_in[1];
  const float* Wq      = (const float*)d_in[2];
  const float* Wk      = (const float*)d_in[3];
  const float* values  = (const float*)d_in[4];

  float* out  = (float*)d_out;
  float* sims = out + (size_t)B_N * H_N;

  // workspace layout (25 MB total)
  char* ws = (char*)d_ws;
  short* q_bf  = (short*)(ws);                                  // 16 MB  [B][512]
  short* k_bf  = (short*)(ws + (16u << 20));                    //  4 MB  [A][512] swz
  short* vt_bf = (short*)(ws + (20u << 20));                    //  4 MB  [512][A] swz
  short* wq_cv = (short*)(ws + (24u << 20));                    // 512 KB
  short* wk_cv = (short*)(ws + (24u << 20) + (512u << 10));     // 512 KB

  convert_w_kernel<<<128, 256, 0, stream>>>(Wq, wq_cv);
  convert_w_kernel<<<128, 256, 0, stream>>>(Wk, wk_cv);
  transpose_values_kernel<<<512, 256, 0, stream>>>(values, vt_bf);
  proj_norm_kernel<0><<<B_N / 64, 256, 0, stream>>>(x, wq_cv, q_bf);
  proj_norm_kernel<1><<<A_N / 64, 256, 0, stream>>>(anchors, wk_cv, k_bf);
  attn_kernel<<<B_N / 64, 512, 0, stream>>>(q_bf, k_bf, vt_bf, out, sims);
}